// Round 12
// baseline (53.595 us; speedup 1.0000x reference)
//
#include <hip/hip_runtime.h>

#define Bn 128
#define Qn 32
#define Dn 512
#define En 300
#define Kn 21
#define NC 16                  // 32-doc chunks per batch
#define CH 32
#define NKT 10                 // k-tiles of 32 floats (320 >= 300, zero-padded)
#define ROWB 640               // bytes per packed q row (320 bf16)
#define SIMLD 36               // sim row stride (floats)
#define NTHR 256
#define QK (Qn * Kn)

typedef __attribute__((ext_vector_type(8))) short bf16x8;
typedef __attribute__((ext_vector_type(4))) float f32x4;

// LDS map (bytes):
//   qbuf [0, 20480)            bf16[32][320], XOR-swizzled rows
//   sim  [20480, 25088)        float[32][SIMLD]
//   invq [25088, 25216)        float[32]
#define SIM_OFF  20480
#define INVQ_OFF 25088
#define SMEM_BYTES 25216

#define SWZ(r, byte) ((byte) ^ (((r) & 7) << 4))   // write+read same (validated R10)

__device__ __forceinline__ float dot4(float4 a, float4 b) {
    return a.x * b.x + a.y * b.y + a.z * b.z + a.w * b.w;
}

// 8 raw CONTIGUOUS floats -> bf16x8, round-half-up (validated R4-R10)
__device__ __forceinline__ bf16x8 pack8r(float4 lo, float4 hi) {
    uint4 u;
    u.x = __builtin_amdgcn_perm(__float_as_uint(lo.y) + 0x8000u,
                                __float_as_uint(lo.x) + 0x8000u, 0x07060302u);
    u.y = __builtin_amdgcn_perm(__float_as_uint(lo.w) + 0x8000u,
                                __float_as_uint(lo.z) + 0x8000u, 0x07060302u);
    u.z = __builtin_amdgcn_perm(__float_as_uint(hi.y) + 0x8000u,
                                __float_as_uint(hi.x) + 0x8000u, 0x07060302u);
    u.w = __builtin_amdgcn_perm(__float_as_uint(hi.w) + 0x8000u,
                                __float_as_uint(hi.z) + 0x8000u, 0x07060302u);
    union { uint4 u4; bf16x8 v; } cv; cv.u4 = u;
    return cv.v;
}

__global__ __launch_bounds__(NTHR, 4)
void knrm_main(const int* __restrict__ qidx, const int* __restrict__ didx,
               const int* __restrict__ dlen_arr, const float* __restrict__ table,
               float* __restrict__ partial)
{
    // XCD-contiguous remap (2048 % 8 == 0, bijective): a batch's 16 blocks share an XCD
    const int g = blockIdx.x;
    const int idx2 = (g & 7) * 256 + (g >> 3);
    const int b = idx2 >> 4;
    const int c = idx2 & 15;
    const int dlen = dlen_arr[b];
    if (c * CH >= dlen) return;      // inactive: reduce kernel never reads this slice

    const int t = threadIdx.x;
    const int lane = t & 63;
    const int w = t >> 6;            // wave -> (qt, dt) quadrant
    const int qt = w >> 1;
    const int dt = w & 1;
    const int frow = lane & 15;
    const int koct = lane >> 4;
    const int row = t >> 3;          // q-staging: one row per 8-lane octet
    const int il  = t & 7;

    __shared__ __align__(16) char smem[SMEM_BYTES];
    char*  qbuf   = smem;
    float* sim    = (float*)(smem + SIM_OFF);
    float* invq_s = (float*)(smem + INVQ_OFF);

    // ---- tokens (direct loads; redundant lanes hit L1)
    const int qstok = qidx[b * Qn + row];                 // staging q token
    const int doc = c * CH + dt * 16 + frow;
    const bool dvalid = (doc < dlen);
    const int dtok = dvalid ? didx[b * Dn + doc] : -1;    // fragment d token
    const float* qsrow = table + (size_t)qstok * En;
    const float* drow  = table + (size_t)dtok * En;
    const float4 z4 = make_float4(0.f, 0.f, 0.f, 0.f);

    // ---- issue q staging loads: CONTIGUOUS 8-float windows at slots il+8i
    float4 lq[NKT];
    #pragma unroll
    for (int i = 0; i < 5; ++i) {
        const int k = (il + 8 * i) * 8;
        lq[2*i]   = (k     <= 296) ? *(const float4*)(qsrow + k)     : z4;
        lq[2*i+1] = (k + 4 <= 296) ? *(const float4*)(qsrow + k + 4) : z4;
    }
    // ---- issue first 3 d-fragment windows (3-deep rotation, 24 regs in flight)
    #define LOADD(dst, KT)                                                        \
        {                                                                         \
            const int f0 = (KT) * 32 + koct * 8;                                  \
            dst[0] = (f0 <= 296 && dtok >= 0) ? *(const float4*)(drow + f0) : z4; \
            dst[1] = (f0 <= 292 && dtok >= 0) ? *(const float4*)(drow + f0 + 4) : z4; \
        }
    float4 dv0[2], dv1[2], dv2[2];
    LOADD(dv0, 0)
    LOADD(dv1, 1)
    LOADD(dv2, 2)

    // ---- q: raw pack + swizzled b128 commit + octet norm -> invq LDS
    float ssq = 0.f;
    #pragma unroll
    for (int i = 0; i < 5; ++i) {
        ssq += dot4(lq[2*i], lq[2*i]) + dot4(lq[2*i+1], lq[2*i+1]);
        const bf16x8 p = pack8r(lq[2*i], lq[2*i+1]);   // bf16 k-range [(il+8i)*8, +8)
        *(bf16x8*)(qbuf + SWZ(row, row * ROWB + (il + 8 * i) * 16)) = p;
    }
    ssq += __shfl_xor(ssq, 1);
    ssq += __shfl_xor(ssq, 2);
    ssq += __shfl_xor(ssq, 4);
    if (il == 0) invq_s[row] = 1.0f / fmaxf(sqrtf(ssq), 1e-12f);

    // ---- d: pack rotation (issue 3 ahead), accumulate ssd
    bf16x8 bfv[NKT];
    float ssd = 0.f;
    #pragma unroll
    for (int kt = 0; kt < NKT; ++kt) {
        float4* cur = (kt % 3 == 0) ? dv0 : (kt % 3 == 1) ? dv1 : dv2;  // static after unroll
        ssd += dot4(cur[0], cur[0]) + dot4(cur[1], cur[1]);
        bfv[kt] = pack8r(cur[0], cur[1]);              // bf16 k-range [kt*32+koct*8, +8)
        if (kt + 3 < NKT) LOADD(cur, kt + 3)
    }
    ssd += __shfl_xor(ssd, 16);
    ssd += __shfl_xor(ssd, 32);
    const float invd = 1.0f / fmaxf(sqrtf(ssd), 1e-12f);

    __syncthreads();                 // qbuf + invq ready

    // ---- 10 MFMAs: A = q from swizzled LDS, B = d from registers
    const int qr0 = qt * 16 + frow;
    f32x4 accS = {0.f, 0.f, 0.f, 0.f};
    #pragma unroll
    for (int kt = 0; kt < NKT; ++kt) {
        const bf16x8 af = *(const bf16x8*)(qbuf + SWZ(qr0, qr0 * ROWB + kt * 64 + koct * 16));
        accS = __builtin_amdgcn_mfma_f32_16x16x32_bf16(af, bfv[kt], accS, 0, 0, 0);
    }
    // C layout: col = frow (doc), row = koct*4 + r (q). Scale by invq*invd here.
    const int dr = dt * 16 + frow;
    #pragma unroll
    for (int r = 0; r < 4; ++r) {
        const int q = qt * 16 + koct * 4 + r;
        sim[q * SIMLD + dr] = accS[r] * invq_s[q] * invd;
    }
    __syncthreads();                 // sim complete

    // ---- pooling: thread = (q row, k-triple); stream 32 docs from sim (R9-proven)
    const int pq = t >> 3;
    const int kg = t & 7;
    if (kg < 7) {
        float mu[3], cf[3];
        #pragma unroll
        for (int kk = 0; kk < 3; ++kk) {
            const int k = kg * 3 + kk;
            mu[kk] = (k == 0) ? 1.0f : 1.05f - 0.1f * (float)k;
            cf[kk] = (k == 0) ? -500000.0f : -50.0f;   // -1/(2*sigma^2)
        }
        float acc[3] = {0.f, 0.f, 0.f};
        const int cbase = c * CH;
        #pragma unroll
        for (int f4 = 0; f4 < 8; ++f4) {
            const float4 sv = *(const float4*)&sim[pq * SIMLD + f4 * 4];
            #pragma unroll
            for (int e = 0; e < 4; ++e) {
                const float se = (e == 0) ? sv.x : (e == 1) ? sv.y : (e == 2) ? sv.z : sv.w;
                const float s = (cbase + f4 * 4 + e < dlen) ? se : 1.0e3f;  // masked -> exp 0
                #pragma unroll
                for (int kk = 0; kk < 3; ++kk) {
                    const float d = s - mu[kk];
                    acc[kk] += __expf(cf[kk] * d * d);
                }
            }
        }
        float* pb = partial + (size_t)(b * NC + c) * QK + pq * Kn + kg * 3;
        pb[0] = acc[0]; pb[1] = acc[1]; pb[2] = acc[2];
    }
}

__global__ __launch_bounds__(704)
void knrm_reduce(const int* __restrict__ qlen_arr, const int* __restrict__ dlen_arr,
                 const float* __restrict__ partial, const float* __restrict__ dense_w,
                 const float* __restrict__ dense_b, float* __restrict__ out)
{
    __shared__ float sq[QK];
    __shared__ float lk[Kn];
    const int b = blockIdx.x;
    const int t = threadIdx.x;
    const int qlen = qlen_arr[b];
    const int ncu = min((dlen_arr[b] + CH - 1) >> 5, NC);   // only written slices
    if (t < QK) {
        const int q = t / Kn;
        float s = 0.f;
        for (int c = 0; c < ncu; ++c)
            s += partial[(size_t)(b * NC + c) * QK + t];
        sq[t] = (q < qlen) ? 0.01f * logf(fmaxf(s, 1e-10f)) : 0.f;
    }
    __syncthreads();
    if (t < Kn) {
        float l = 0.f;
        #pragma unroll
        for (int q = 0; q < Qn; ++q) l += sq[q * Kn + t];
        out[Bn + (size_t)b * Kn + t] = l;   // log_pooling_sum (B,K)
        lk[t] = l;
    }
    __syncthreads();
    if (t == 0) {
        float sc = dense_b[0];
        #pragma unroll
        for (int k = 0; k < Kn; ++k) sc += lk[k] * dense_w[k];
        out[b] = sc;                        // score (B,)
    }
}

extern "C" void kernel_launch(void* const* d_in, const int* in_sizes, int n_in,
                              void* d_out, int out_size, void* d_ws, size_t ws_size,
                              hipStream_t stream)
{
    const int*   qidx  = (const int*)d_in[0];
    const int*   didx  = (const int*)d_in[1];
    const int*   qlen  = (const int*)d_in[2];
    const int*   dlen  = (const int*)d_in[3];
    const float* table = (const float*)d_in[4];
    const float* dw    = (const float*)d_in[5];
    const float* db    = (const float*)d_in[6];
    float* out     = (float*)d_out;
    float* partial = (float*)d_ws;   // 5.5 MB; only slices with c < ceil(dlen/32) are read

    knrm_main<<<dim3(Bn * NC), dim3(NTHR), 0, stream>>>(qidx, didx, dlen, table, partial);
    knrm_reduce<<<dim3(Bn), dim3(704), 0, stream>>>(qlen, dlen, partial, dw, db, out);
}

// Round 13
// 29.289 us; speedup vs baseline: 1.8299x; 1.8299x over previous
//
#include <hip/hip_runtime.h>

#define Bn 128
#define Qn 32
#define Dn 512
#define En 300
#define Kn 21
#define NC 16                  // 32-doc chunks per batch
#define CH 32
#define NKT 10                 // k-tiles of 32 (covers 320 >= 300, zero-padded)
#define LDE 40                 // shorts per row within one k-tile (80 B)
#define TILE_SH (CH * LDE)     // 1280 shorts per k-tile
#define SIMLD 36               // sim row stride (floats)
#define NTHR 256
#define QK (Qn * Kn)           // 672 partials per (b,c)

typedef __attribute__((ext_vector_type(8))) short bf16x8;
typedef __attribute__((ext_vector_type(4))) float f32x4;

// LDS map (bytes):
//   dbuf [0, 25600)       short[NKT][CH][LDE]
//   qbuf [25600, 51200)   same; dead after af-hoist -> sim float[32][SIMLD] aliases it
//   idx  [51200, 51456)   int[64]: 32 doc tokens, 32 q tokens
#define SMEM_BYTES 51456       // -> 3 blocks/CU

__device__ __forceinline__ float dot4(float4 a, float4 b) {
    return a.x * b.x + a.y * b.y + a.z * b.z + a.w * b.w;
}

#define ISSUE(arr, tok)                                                        \
    _Pragma("unroll")                                                          \
    for (int j2 = 0; j2 < NKT; ++j2) {                                         \
        const int k = j2 * 32 + il * 4;                                        \
        float4 v = {0.f, 0.f, 0.f, 0.f};                                       \
        if (k <= 296 && (tok) >= 0)                                            \
            v = *(const float4*)(table + (size_t)(tok) * En + k);              \
        arr[j2] = v;                                                           \
    }

#define COMMIT(arr, dst)                                                       \
    {                                                                          \
        float ss = 0.f;                                                        \
        _Pragma("unroll")                                                      \
        for (int j2 = 0; j2 < NKT; ++j2) ss += dot4(arr[j2], arr[j2]);         \
        ss += __shfl_xor(ss, 1);                                               \
        ss += __shfl_xor(ss, 2);                                               \
        ss += __shfl_xor(ss, 4);                                               \
        const float inv = 1.0f / fmaxf(sqrtf(ss), 1e-12f);                     \
        _Pragma("unroll")                                                      \
        for (int j2 = 0; j2 < NKT; ++j2) {                                     \
            const unsigned ax = __float_as_uint(arr[j2].x * inv) + 0x8000u;    \
            const unsigned ay = __float_as_uint(arr[j2].y * inv) + 0x8000u;    \
            const unsigned az = __float_as_uint(arr[j2].z * inv) + 0x8000u;    \
            const unsigned aw = __float_as_uint(arr[j2].w * inv) + 0x8000u;    \
            uint2 p;                                                           \
            p.x = __builtin_amdgcn_perm(ay, ax, 0x07060302u);                  \
            p.y = __builtin_amdgcn_perm(aw, az, 0x07060302u);                  \
            *(uint2*)&(dst)[j2 * TILE_SH + row * LDE + il * 4] = p;            \
        }                                                                      \
    }

__global__ __launch_bounds__(NTHR, 3)
void knrm_main(const int* __restrict__ qidx, const int* __restrict__ didx,
               const int* __restrict__ dlen_arr, const float* __restrict__ table,
               float* __restrict__ partial)
{
    // XCD-contiguous remap (2048 % 8 == 0, bijective): a batch's 16 blocks share an XCD
    const int g = blockIdx.x;
    const int idx2 = (g & 7) * 256 + (g >> 3);
    const int b = idx2 >> 4;
    const int c = idx2 & 15;
    const int dlen = dlen_arr[b];
    if (c * CH >= dlen) return;      // inactive: reduce kernel never reads this slice

    const int t = threadIdx.x;

    __shared__ __align__(16) char smem[SMEM_BYTES];
    short* dbuf = (short*)smem;
    short* qbuf = (short*)(smem + 25600);
    float* sim  = (float*)(smem + 25600);     // alias: live only after af-hoist sync
    int*   idxb = (int*)(smem + 51200);       // [64]

    // ---- stage tokens (-1 sentinel -> zero rows)
    if (t < CH) {
        const int doc = c * CH + t;
        idxb[t] = (doc < dlen) ? didx[b * Dn + doc] : -1;
    } else if (t < CH + Qn) {
        idxb[t] = qidx[b * Qn + (t - CH)];
    }
    __syncthreads();

    const int row = t >> 3;      // 32 rows, one per 8-lane octet
    const int il  = t & 7;

    // ---- issue q and d gathers together (one latency window), commit both
    float4 lq[NKT], ldd[NKT];
    const int qtok = idxb[CH + row];
    const int dtok = idxb[row];
    ISSUE(lq, qtok)
    ISSUE(ldd, dtok)
    COMMIT(lq, qbuf)
    COMMIT(ldd, dbuf)
    __syncthreads();             // qbuf+dbuf ready

    const int lane = t & 63;
    const int w = t >> 6;
    const int qt = w >> 1;
    const int dt = w & 1;
    const int frow = lane & 15;
    const int koct = lane >> 4;

    bf16x8 af[NKT];
    #pragma unroll
    for (int kt = 0; kt < NKT; ++kt)
        af[kt] = *(const bf16x8*)&qbuf[kt * TILE_SH + (qt * 16 + frow) * LDE + koct * 8];
    __syncthreads();             // all waves hoisted; qbuf dead -> sim alias live

    f32x4 accS = {0.f, 0.f, 0.f, 0.f};
    #pragma unroll
    for (int kt = 0; kt < NKT; ++kt) {
        bf16x8 bf = *(const bf16x8*)&dbuf[kt * TILE_SH + (dt * 16 + frow) * LDE + koct * 8];
        accS = __builtin_amdgcn_mfma_f32_16x16x32_bf16(af[kt], bf, accS, 0, 0, 0);
    }
    // C layout: col=frow (doc), row=koct*4+r (q within tile)
    #pragma unroll
    for (int r = 0; r < 4; ++r)
        sim[(qt * 16 + koct * 4 + r) * SIMLD + dt * 16 + frow] = accS[r];
    __syncthreads();

    // ---- pooling: thread = (q row, doc-quad); factorized Gaussian kernels.
    // exp(-50(s-mu_k)^2) = a * rr^k * exp(-50 mu_k^2), a=exp(-50s^2+105s),
    // rr=exp(-10s); chain is symmetric in |s|, sign picks fill direction.
    // exp(-50 mu_k^2) is applied in the reduce kernel (folds into the log).
    const int pq = t >> 3;           // q row
    const int dl = t & 7;            // doc-quad
    const int cbase = c * CH + dl * 4;
    const float4 sv = *(const float4*)&sim[pq * SIMLD + dl * 4];  // conflict-free b128

    float acc[Kn];
    #pragma unroll
    for (int k = 0; k < Kn; ++k) acc[k] = 0.f;

    float sarr[4];
    sarr[0] = (cbase + 0 < dlen) ? sv.x : 1.0e3f;   // sentinel -> all terms 0
    sarr[1] = (cbase + 1 < dlen) ? sv.y : 1.0e3f;
    sarr[2] = (cbase + 2 < dlen) ? sv.z : 1.0e3f;
    sarr[3] = (cbase + 3 < dlen) ? sv.w : 1.0e3f;

    #pragma unroll
    for (int j = 0; j < 4; ++j) {
        const float sj = sarr[j];
        const float sm1 = sj - 1.0f;
        acc[0] += __expf(-500000.f * sm1 * sm1);       // k=0, sigma=0.001
        const float sa = fabsf(sj);
        float x = __expf((105.f - 50.f * sa) * sa);    // bounded by e^55
        const float rr = __expf(-10.f * sa);
        if (sj >= 0.f) {
            #pragma unroll
            for (int k = 1; k <= 20; ++k) { x *= rr; acc[k] += x; }
        } else {
            #pragma unroll
            for (int k = 1; k <= 20; ++k) { x *= rr; acc[21 - k] += x; }
        }
    }

    // ---- reduce over the 8 doc-quads of each q (in-wave butterfly)
    #pragma unroll
    for (int k = 0; k < Kn; ++k) {
        acc[k] += __shfl_xor(acc[k], 1);
        acc[k] += __shfl_xor(acc[k], 2);
        acc[k] += __shfl_xor(acc[k], 4);
    }
    if (dl == 0) {
        float* pb = partial + (size_t)(b * NC + c) * QK + pq * Kn;
        #pragma unroll
        for (int k = 0; k < Kn; ++k) pb[k] = acc[k];
    }
}

__global__ __launch_bounds__(704)
void knrm_reduce(const int* __restrict__ qlen_arr, const int* __restrict__ dlen_arr,
                 const float* __restrict__ partial, const float* __restrict__ dense_w,
                 const float* __restrict__ dense_b, float* __restrict__ out)
{
    __shared__ float sq[QK];
    __shared__ float lk[Kn];
    const int b = blockIdx.x;
    const int t = threadIdx.x;
    const int qlen = qlen_arr[b];
    const int ncu = min((dlen_arr[b] + CH - 1) >> 5, NC);   // only written slices
    if (t < QK) {
        const int q = t / Kn;
        const int k = t - q * Kn;
        float s = 0.f;
        for (int c = 0; c < ncu; ++c)
            s += partial[(size_t)(b * NC + c) * QK + t];
        if (k > 0) {                                   // fold exp(-50 mu_k^2) back in
            const float mk = 1.05f - 0.1f * (float)k;
            s *= __expf(-50.f * mk * mk);
        }
        sq[t] = (q < qlen) ? 0.01f * logf(fmaxf(s, 1e-10f)) : 0.f;
    }
    __syncthreads();
    if (t < Kn) {
        float l = 0.f;
        #pragma unroll
        for (int q = 0; q < Qn; ++q) l += sq[q * Kn + t];
        out[Bn + (size_t)b * Kn + t] = l;   // log_pooling_sum (B,K)
        lk[t] = l;
    }
    __syncthreads();
    if (t == 0) {
        float sc = dense_b[0];
        #pragma unroll
        for (int k = 0; k < Kn; ++k) sc += lk[k] * dense_w[k];
        out[b] = sc;                        // score (B,)
    }
}

extern "C" void kernel_launch(void* const* d_in, const int* in_sizes, int n_in,
                              void* d_out, int out_size, void* d_ws, size_t ws_size,
                              hipStream_t stream)
{
    const int*   qidx  = (const int*)d_in[0];
    const int*   didx  = (const int*)d_in[1];
    const int*   qlen  = (const int*)d_in[2];
    const int*   dlen  = (const int*)d_in[3];
    const float* table = (const float*)d_in[4];
    const float* dw    = (const float*)d_in[5];
    const float* db    = (const float*)d_in[6];
    float* out     = (float*)d_out;
    float* partial = (float*)d_ws;   // 5.5 MB; only slices with c < ceil(dlen/32) are read

    knrm_main<<<dim3(Bn * NC), dim3(NTHR), 0, stream>>>(qidx, didx, dlen, table, partial);
    knrm_reduce<<<dim3(Bn), dim3(704), 0, stream>>>(qlen, dlen, partial, dw, db, out);
}